// Round 6
// baseline (166.340 us; speedup 1.0000x reference)
//
#include <hip/hip_runtime.h>
#include <hip/hip_bf16.h>

// Problem constants
#define SRC    16384     // 128*128 source pixels
#define DCH    64        // channels
#define NCLS   19        // classes
#define NPAIR  (NCLS*DCH)// 1216 (c,d) pairs
#define NCHUNK 256       // K1 blocks: 64-pixel chunks
#define CPX    64        // pixels per chunk
#define KSPLIT 2         // pixel-split blocks per pair in the KDE kernel
#define NITEM  (NPAIR*KSPLIT)

// Bare v_exp_f32 (args in [-450,0]; underflow->0 matches reference f32 exp).
#if defined(__has_builtin)
#if __has_builtin(__builtin_amdgcn_exp2f)
#define EXP2F(x) __builtin_amdgcn_exp2f(x)
#else
#define EXP2F(x) __exp2f(x)
#endif
#else
#define EXP2F(x) __exp2f(x)
#endif

// ---------------------------------------------------------------------------
// K1: fused count + moments.
// Block = one 64-pixel chunk (half a source row). Phase A: threads 0..63
// compute per-pixel class counts from the 4x4 label blocks -> LDS + global
// cnt (kde needs it). Phase B: thread (d=t&63, g=t>>6) holds 16 x's in
// registers, accumulates a1[c]=sum cv*x, a2[c]=sum cv*x^2 over 19 classes
// (cnt read from LDS, wave-uniform broadcast). Fixed-order LDS block reduce,
// then f64 atomic adds into S1/S2 (contiguous 512B segments per wave) and
// int atomics into ncls. Atomic order only perturbs ~1e-15 rel.
// ---------------------------------------------------------------------------
__global__ __launch_bounds__(256) void hl_cm_kernel(
    const float* __restrict__ feature, const int* __restrict__ label,
    unsigned char* __restrict__ cnt,
    double* __restrict__ S1, double* __restrict__ S2, int* __restrict__ ncls)
{
    int cb = blockIdx.x;            // chunk 0..255
    int t  = threadIdx.x;
    int d  = t & 63, g = t >> 6;    // g = wave id (0..3)
    int s0 = cb * CPX;

    __shared__ uint4 cl4[NCLS][4];  // [class][16B group] = counts for 64 px
    unsigned char* cl = (unsigned char*)cl4;   // row stride 64

    // ---- Phase A: per-pixel class counts (threads 0..63, one pixel each) --
    if (t < 64) {
        int s  = s0 + t;
        int sy = s >> 7, sx = s & 127;
        const int4* lab4 = (const int4*)label;
        int l[16];
#pragma unroll
        for (int r = 0; r < 4; r++) {
            int4 v = lab4[(4 * sy + r) * 128 + sx];
            l[4 * r + 0] = v.x; l[4 * r + 1] = v.y;
            l[4 * r + 2] = v.z; l[4 * r + 3] = v.w;
        }
#pragma unroll
        for (int c = 0; c < NCLS; c++) {
            int cc = 0;
#pragma unroll
            for (int j = 0; j < 16; j++) cc += (l[j] == c) ? 1 : 0;
            cl[c * 64 + t] = (unsigned char)cc;
            cnt[c * SRC + s] = (unsigned char)cc;
        }
    }
    __syncthreads();

    // ---- ncls partials: threads 0..18 SWAR-sum their class row -----------
    if (t < NCLS) {
        int n = 0;
#pragma unroll
        for (int i = 0; i < 4; i++) {
            uint4 v = cl4[t][i];
            unsigned int ww[4] = {v.x, v.y, v.z, v.w};
#pragma unroll
            for (int q = 0; q < 4; q++)
                n += (ww[q] & 0xFF) + ((ww[q] >> 8) & 0xFF) +
                     ((ww[q] >> 16) & 0xFF) + (ww[q] >> 24);
        }
        atomicAdd(&ncls[t], n);
    }

    // ---- Phase B: register moments over 19 classes ------------------------
    const float4* f4 = (const float4*)(feature + d * SRC + s0 + 16 * g);
    float xs[16];
#pragma unroll
    for (int i = 0; i < 4; i++) {
        float4 v = f4[i];
        xs[4 * i + 0] = v.x; xs[4 * i + 1] = v.y;
        xs[4 * i + 2] = v.z; xs[4 * i + 3] = v.w;
    }

    float a1[NCLS], a2[NCLS];
#pragma unroll
    for (int c = 0; c < NCLS; c++) {
        uint4 cw = cl4[c][g];       // wave-uniform -> LDS broadcast
        unsigned int wdw[4] = {cw.x, cw.y, cw.z, cw.w};
        float s1 = 0.f, s2 = 0.f;
#pragma unroll
        for (int q = 0; q < 4; q++) {
#pragma unroll
            for (int b = 0; b < 4; b++) {
                float cv = (float)((wdw[q] >> (8 * b)) & 0xFFu);
                float x  = xs[4 * q + b];
                float wx = cv * x;
                s1 += wx;
                s2 = fmaf(wx, x, s2);
            }
        }
        a1[c] = s1; a2[c] = s2;
    }

    // ---- fixed-order cross-wave reduce then global f64 atomics -----------
    __shared__ float b1[NPAIR], b2[NPAIR];
#pragma unroll
    for (int r = 0; r < 4; r++) {
        if (g == r) {
            if (r == 0) {
#pragma unroll
                for (int c = 0; c < NCLS; c++) { b1[c * 64 + d] = a1[c]; b2[c * 64 + d] = a2[c]; }
            } else {
#pragma unroll
                for (int c = 0; c < NCLS; c++) { b1[c * 64 + d] += a1[c]; b2[c * 64 + d] += a2[c]; }
            }
        }
        __syncthreads();
    }
    for (int i = t; i < NPAIR; i += 256) {
        __hip_atomic_fetch_add(&S1[i], (double)b1[i],
                               __ATOMIC_RELAXED, __HIP_MEMORY_SCOPE_AGENT);
        __hip_atomic_fetch_add(&S2[i], (double)b2[i],
                               __ATOMIC_RELAXED, __HIP_MEMORY_SCOPE_AGENT);
    }
}

// ---------------------------------------------------------------------------
// K2: KDE + last-block loss.
// KSPLIT blocks per (c,d), each covering SRC/KSPLIT pixels.
// C1*(u-k)^2 = q - 2k*p + C1*k^2 with p = C1*u, q = p*u; bare v_exp_f32.
// The 1/sqrt(2*pi*var_s) factor cancels in normalization. After writing its
// 7-slot partial, each block ticket-arrives (release fence + device atomic);
// the LAST block alone re-reads all partials (acquire fence) and computes
// the final smooth-L1 loss. Single arrival each -> no spin contention.
// ---------------------------------------------------------------------------
__global__ __launch_bounds__(1024) void hl_kde_kernel(
    const float* __restrict__ feature, const unsigned char* __restrict__ cnt,
    const double* __restrict__ S1d, const double* __restrict__ S2d,
    const int* __restrict__ ncls, float* __restrict__ sample,
    unsigned* __restrict__ ticket, float* __restrict__ out)
{
    int blk  = blockIdx.x;          // 0..NITEM-1
    int w    = blk >> 1;            // pair
    int half = blk & 1;
    int c = w >> 6, d = w & 63;
    int tid = threadIdx.x;
    int wid = tid >> 6;

    __shared__ float sh_mu, sh_istd;
    __shared__ int   sh_last;
    if (tid == 0) {
        int    n     = ncls[c];
        double nsafe = (n > 0) ? (double)n : 1.0;
        double s1 = S1d[w], s2 = S2d[w];
        double mu  = s1 / nsafe;
        double var = (s2 - 2.0 * mu * s1 + mu * mu * (double)n) / nsafe + 1e-10;
        sh_mu   = (float)mu;
        sh_istd = (float)(1.0 / sqrt(var));
    }
    __syncthreads();
    float istd = sh_istd;
    float nm   = -sh_mu * istd;     // u = fma(x, istd, nm)

    const float4*       fp4 = (const float4*)(feature + d * SRC);
    const unsigned int* cp4 = (const unsigned int*)(cnt + c * SRC);

    const float C1 = -18.033688011112042f;   // -12.5 * log2(e)
    float acc[7] = {0.f, 0.f, 0.f, 0.f, 0.f, 0.f, 0.f};

#pragma unroll
    for (int i = 0; i < 2; i++) {
        int g = half * 2048 + i * 1024 + tid;   // 2048 float4-groups per half
        float4       x  = fp4[g];
        unsigned int cv = cp4[g];
        float xsl[4] = {x.x, x.y, x.z, x.w};
        float cfl[4] = {(float)(cv & 255u), (float)((cv >> 8) & 255u),
                        (float)((cv >> 16) & 255u), (float)(cv >> 24)};
#pragma unroll
        for (int e = 0; e < 4; e++) {
            float u = fmaf(xsl[e], istd, nm);
            float p = C1 * u;
            float q = p * u;                     // C1*u^2
#pragma unroll
            for (int k = 0; k < 7; k++) {
                float km  = (float)(k - 3);
                float arg = fmaf(p, -2.f * km, q + C1 * km * km);
                acc[k] = fmaf(cfl[e], EXP2F(arg), acc[k]);
            }
        }
    }

    __shared__ float part[16][7];
#pragma unroll
    for (int j = 0; j < 7; j++) {
        float v = acc[j];
#pragma unroll
        for (int o = 32; o > 0; o >>= 1) v += __shfl_down(v, o);
        if ((tid & 63) == 0) part[wid][j] = v;
    }
    __syncthreads();
    if (tid < 7) {
        float v = 0.f;
#pragma unroll
        for (int i = 0; i < 16; i++) v += part[i][tid];
        sample[blk * 7 + tid] = v;
    }

    // ---- ticket arrival (release) ----------------------------------------
    __syncthreads();
    if (tid == 0) {
        __threadfence();            // drain + make sample stores agent-visible
        unsigned old = __hip_atomic_fetch_add(ticket, 1u, __ATOMIC_ACQ_REL,
                                              __HIP_MEMORY_SCOPE_AGENT);
        sh_last = (old == (unsigned)(NITEM - 1));
    }
    __syncthreads();
    if (!sh_last) return;
    __threadfence();                // acquire: see all blocks' sample stores

    // ---- final loss (last block only) ------------------------------------
    float targ[7];
    {
        double e[7], z = 0.0;
#pragma unroll
        for (int k = -3; k <= 3; k++) { e[k + 3] = exp(-0.5 * (double)(k * k)); z += e[k + 3]; }
#pragma unroll
        for (int j = 0; j < 7; j++) targ[j] = (float)(e[j] / z);
    }

    float lsum = 0.f, asum = 0.f;
    for (int p = tid; p < NPAIR; p += 1024) {
        int cc = p >> 6;
        int n  = ncls[cc];
        if (n < 1000) continue;              // inactive class
        float sv[7], S = 0.f;
#pragma unroll
        for (int j = 0; j < 7; j++) {
            sv[j] = sample[(2 * p) * 7 + j] + sample[(2 * p + 1) * 7 + j];
            S += sv[j];
        }
        float Ss = fmaxf(S, 1e-30f);
        float ps = 0.f;
#pragma unroll
        for (int j = 0; j < 7; j++) {
            float dd = fabsf(sv[j] / Ss - targ[j]);
            ps += (dd < 1.f) ? 0.5f * dd * dd : (dd - 0.5f);
        }
        lsum += ps;
        if ((p & 63) == 0) asum += 1.f;      // count each active class once
    }
#pragma unroll
    for (int o = 32; o > 0; o >>= 1) {
        lsum += __shfl_down(lsum, o);
        asum += __shfl_down(asum, o);
    }
    __shared__ float lw[16], aw[16];
    if ((tid & 63) == 0) { lw[wid] = lsum; aw[wid] = asum; }
    __syncthreads();
    if (tid == 0) {
        float L = 0.f, A = 0.f;
#pragma unroll
        for (int i = 0; i < 16; i++) { L += lw[i]; A += aw[i]; }
        out[0] = (A > 0.f) ? (L / 448.0f) / A : 0.0f;  // mean over D*7=448, /active
    }
}

// ---------------------------------------------------------------------------
extern "C" void kernel_launch(void* const* d_in, const int* in_sizes, int n_in,
                              void* d_out, int out_size, void* d_ws, size_t ws_size,
                              hipStream_t stream)
{
    const float* feature = (const float*)d_in[0];   // [1,64,128,128] fp32
    const int*   label   = (const int*)d_in[1];     // [1,1,512,512]  int32
    float*       out     = (float*)d_out;           // scalar fp32

    char* ws = (char*)d_ws;
    unsigned char* cnt    = (unsigned char*)(ws);          // 311296 B
    double*        S1     = (double*)(ws + 311296);        // 9728 B
    double*        S2     = (double*)(ws + 321024);        // 9728 B
    int*           ncls   = (int*)(ws + 330752);           // 76 B
    unsigned*      ticket = (unsigned*)(ws + 330828);      // 4 B
    float*         sample = (float*)(ws + 330880);         // 2432*7*4 = 68096 B

    // zero the accumulation targets (S1,S2,ncls,ticket) in one thin node
    hipMemsetAsync(ws + 311296, 0, 19584, stream);
    hl_cm_kernel <<<NCHUNK, 256, 0, stream>>>(feature, label, cnt, S1, S2, ncls);
    hl_kde_kernel<<<NITEM, 1024, 0, stream>>>(feature, cnt, S1, S2, ncls,
                                              sample, ticket, out);
}

// Round 7
// 117.891 us; speedup vs baseline: 1.4110x; 1.4110x over previous
//
#include <hip/hip_runtime.h>
#include <hip/hip_bf16.h>

// Problem constants
#define SRC    16384     // 128*128 source pixels
#define DCH    64        // channels
#define NCLS   19        // classes
#define NPAIR  (NCLS*DCH)// 1216 (c,d) pairs

// Bare v_exp_f32 (args in [-450,0]; underflow->0 matches reference f32 exp).
#if defined(__has_builtin)
#if __has_builtin(__builtin_amdgcn_exp2f)
#define EXP2F(x) __builtin_amdgcn_exp2f(x)
#else
#define EXP2F(x) __exp2f(x)
#endif
#else
#define EXP2F(x) __exp2f(x)
#endif

// ---------------------------------------------------------------------------
// K1: per-source-pixel class counts. Each source pixel covers a 4x4 block of
// the 512x512 label map. cnt[c*SRC + s] = #subpixels with label c (0..16).
// Also zeroes out[0] (harness poisons d_out before every timed launch; K3's
// atomicAdds accumulate into it downstream in stream order).
// ---------------------------------------------------------------------------
__global__ __launch_bounds__(256) void hl_count_kernel(
    const int* __restrict__ label, unsigned char* __restrict__ cnt,
    float* __restrict__ out)
{
    if (blockIdx.x == 0 && threadIdx.x == 0) out[0] = 0.f;
    int s  = blockIdx.x * 256 + threadIdx.x;   // 64 blocks x 256 = 16384
    int sy = s >> 7, sx = s & 127;
    const int4* lab4 = (const int4*)label;
    int l[16];
#pragma unroll
    for (int r = 0; r < 4; r++) {
        int4 v = lab4[(4 * sy + r) * 128 + sx];
        l[4 * r + 0] = v.x; l[4 * r + 1] = v.y;
        l[4 * r + 2] = v.z; l[4 * r + 3] = v.w;
    }
#pragma unroll
    for (int c = 0; c < NCLS; c++) {
        int cc = 0;
#pragma unroll
        for (int j = 0; j < 16; j++) cc += (l[j] == c) ? 1 : 0;
        cnt[c * SRC + s] = (unsigned char)cc;
    }
}

// ---------------------------------------------------------------------------
// K2: moments. One 256-thread block (4 waves) per (c,d); 64 px/thread via
// 16 coalesced float4 + 16 coalesced uint loads (32 outstanding loads).
// All 1216 blocks co-resident in one round (4864 waves < 8192 slots).
// f32 thread partials -> f64 shuffle reduce -> f64 LDS combine. No atomics.
// ---------------------------------------------------------------------------
__global__ __launch_bounds__(256) void hl_moments_kernel(
    const float* __restrict__ feature, const unsigned char* __restrict__ cnt,
    double* __restrict__ S1, double* __restrict__ S2, int* __restrict__ ncls)
{
    int w = blockIdx.x;             // pair 0..1215
    int c = w >> 6, d = w & 63;
    int t = threadIdx.x;

    const float4*       fp4 = (const float4*)(feature + d * SRC);
    const unsigned int* cpu = (const unsigned int*)(cnt + c * SRC);

    float f1 = 0.f, f2 = 0.f;
    int   nc = 0;
#pragma unroll
    for (int i = 0; i < 16; i++) {
        int g = i * 256 + t;        // 4096 float4-groups (= 4096 uint count-groups)
        float4       x  = fp4[g];
        unsigned int cv = cpu[g];
        float xs[4] = {x.x, x.y, x.z, x.w};
        float cf[4] = {(float)(cv & 255u), (float)((cv >> 8) & 255u),
                       (float)((cv >> 16) & 255u), (float)(cv >> 24)};
#pragma unroll
        for (int e = 0; e < 4; e++) {
            float wx = cf[e] * xs[e];
            f1 += wx;
            f2 = fmaf(wx, xs[e], f2);
        }
        nc += (cv & 255u) + ((cv >> 8) & 255u) + ((cv >> 16) & 255u) + (cv >> 24);
    }
    double s1 = (double)f1, s2 = (double)f2;
#pragma unroll
    for (int o = 32; o > 0; o >>= 1) {
        s1 += __shfl_down(s1, o);
        s2 += __shfl_down(s2, o);
        nc += __shfl_down(nc, o);
    }
    __shared__ double ps1[4], ps2[4];
    __shared__ int    pn[4];
    int wid = t >> 6;
    if ((t & 63) == 0) { ps1[wid] = s1; ps2[wid] = s2; pn[wid] = nc; }
    __syncthreads();
    if (t == 0) {
        double a = ps1[0] + ps1[1] + ps1[2] + ps1[3];
        double b = ps2[0] + ps2[1] + ps2[2] + ps2[3];
        int    n = pn[0] + pn[1] + pn[2] + pn[3];
        S1[w] = a; S2[w] = b;
        if (d == 0) ncls[c] = n;
    }
}

// ---------------------------------------------------------------------------
// K3: KDE + per-pair loss. One 256-thread block per (c,d), 64 px/thread.
// u = (x-mu)/std; C1*(u-k)^2 = q - 2k*p + C1*k^2 with p=C1*u, q=p*u; bare
// v_exp_f32 (the 1/sqrt(2*pi*var_s) factor cancels in normalization).
// Block reduces its 7-bin histogram, normalizes, computes the smooth-L1
// partial for its pair and atomicAdds ps/(448*A) into out[0]. 1216 f32
// atomics total (order noise ~1e-9 << 2.7e-7 budget). No fences.
// ---------------------------------------------------------------------------
__global__ __launch_bounds__(256) void hl_kde_kernel(
    const float* __restrict__ feature, const unsigned char* __restrict__ cnt,
    const double* __restrict__ S1d, const double* __restrict__ S2d,
    const int* __restrict__ ncls, float* __restrict__ out)
{
    int w = blockIdx.x;             // pair 0..1215
    int c = w >> 6, d = w & 63;
    int t = threadIdx.x;
    int wid = t >> 6;

    __shared__ float sh_mu, sh_istd;
    __shared__ int   sh_act;
    if (t == 0) {
        int    n     = ncls[c];
        double nsafe = (n > 0) ? (double)n : 1.0;
        double s1 = S1d[w], s2 = S2d[w];
        double mu  = s1 / nsafe;
        double var = (s2 - 2.0 * mu * s1 + mu * mu * (double)n) / nsafe + 1e-10;
        sh_mu   = (float)mu;
        sh_istd = (float)(1.0 / sqrt(var));
        sh_act  = (n >= 1000);
    }
    __syncthreads();
    if (!sh_act) return;            // inactive class: contributes 0
    float istd = sh_istd;
    float nm   = -sh_mu * istd;     // u = fma(x, istd, nm)

    const float4*       fp4 = (const float4*)(feature + d * SRC);
    const unsigned int* cpu = (const unsigned int*)(cnt + c * SRC);

    const float C1 = -18.033688011112042f;   // -12.5 * log2(e)
    float acc[7] = {0.f, 0.f, 0.f, 0.f, 0.f, 0.f, 0.f};

#pragma unroll
    for (int i = 0; i < 16; i++) {
        int g = i * 256 + t;
        float4       x  = fp4[g];
        unsigned int cv = cpu[g];
        float xs[4] = {x.x, x.y, x.z, x.w};
        float cf[4] = {(float)(cv & 255u), (float)((cv >> 8) & 255u),
                       (float)((cv >> 16) & 255u), (float)(cv >> 24)};
#pragma unroll
        for (int e = 0; e < 4; e++) {
            float u = fmaf(xs[e], istd, nm);
            float p = C1 * u;
            float q = p * u;                 // C1*u^2
#pragma unroll
            for (int k = 0; k < 7; k++) {
                float km  = (float)(k - 3);
                float arg = fmaf(p, -2.f * km, q + C1 * km * km);
                acc[k] = fmaf(cf[e], EXP2F(arg), acc[k]);
            }
        }
    }

    __shared__ float part[4][7];
#pragma unroll
    for (int j = 0; j < 7; j++) {
        float v = acc[j];
#pragma unroll
        for (int o = 32; o > 0; o >>= 1) v += __shfl_down(v, o);
        if ((t & 63) == 0) part[wid][j] = v;
    }
    __syncthreads();

    if (t == 0) {
        // target: exp(-0.5 k^2)/Z (1/sqrt(2 pi var) cancels in normalization)
        double e[7], z = 0.0;
#pragma unroll
        for (int k = -3; k <= 3; k++) { e[k + 3] = exp(-0.5 * (double)(k * k)); z += e[k + 3]; }

        float hist[7], S = 0.f;
#pragma unroll
        for (int j = 0; j < 7; j++) {
            hist[j] = part[0][j] + part[1][j] + part[2][j] + part[3][j];
            S += hist[j];
        }
        float Ss = fmaxf(S, 1e-30f);
        float ps = 0.f;
#pragma unroll
        for (int j = 0; j < 7; j++) {
            float dd = fabsf(hist[j] / Ss - (float)(e[j] / z));
            ps += (dd < 1.f) ? 0.5f * dd * dd : (dd - 0.5f);
        }
        int A = 0;
#pragma unroll
        for (int i = 0; i < NCLS; i++) A += (ncls[i] >= 1000) ? 1 : 0;
        atomicAdd(out, ps / (448.0f * (float)A));
    }
}

// ---------------------------------------------------------------------------
extern "C" void kernel_launch(void* const* d_in, const int* in_sizes, int n_in,
                              void* d_out, int out_size, void* d_ws, size_t ws_size,
                              hipStream_t stream)
{
    const float* feature = (const float*)d_in[0];   // [1,64,128,128] fp32
    const int*   label   = (const int*)d_in[1];     // [1,1,512,512]  int32
    float*       out     = (float*)d_out;           // scalar fp32

    char* ws = (char*)d_ws;
    unsigned char* cnt  = (unsigned char*)(ws);      // 311296 B
    double*        S1   = (double*)(ws + 311296);    // 9728 B
    double*        S2   = (double*)(ws + 321024);    // 9728 B
    int*           ncls = (int*)(ws + 330752);       // 76 B

    hl_count_kernel  <<<SRC / 256, 256, 0, stream>>>(label, cnt, out);
    hl_moments_kernel<<<NPAIR, 256, 0, stream>>>(feature, cnt, S1, S2, ncls);
    hl_kde_kernel    <<<NPAIR, 256, 0, stream>>>(feature, cnt, S1, S2, ncls, out);
}

// Round 8
// 90.271 us; speedup vs baseline: 1.8427x; 1.3060x over previous
//
#include <hip/hip_runtime.h>
#include <hip/hip_bf16.h>

// Problem constants
#define SRC    16384     // 128*128 source pixels
#define DCH    64        // channels
#define NCLS   19        // classes
#define NPAIR  (NCLS*DCH)// 1216 (c,d) pairs

// Bare v_exp_f32 (args in [-450,0]; underflow->0 matches reference f32 exp).
#if defined(__has_builtin)
#if __has_builtin(__builtin_amdgcn_exp2f)
#define EXP2F(x) __builtin_amdgcn_exp2f(x)
#else
#define EXP2F(x) __exp2f(x)
#endif
#else
#define EXP2F(x) __exp2f(x)
#endif

// ---------------------------------------------------------------------------
// K1: per-source-pixel class counts. Each source pixel covers a 4x4 block of
// the 512x512 label map. cnt[c*SRC + s] = #subpixels with label c (0..16).
// Also zeroes out[0] (harness poisons d_out; K3 atomically accumulates into
// it in stream order).
// ---------------------------------------------------------------------------
__global__ __launch_bounds__(256) void hl_count_kernel(
    const int* __restrict__ label, unsigned char* __restrict__ cnt,
    float* __restrict__ out)
{
    if (blockIdx.x == 0 && threadIdx.x == 0) out[0] = 0.f;
    int s  = blockIdx.x * 256 + threadIdx.x;   // 64 blocks x 256 = 16384
    int sy = s >> 7, sx = s & 127;
    const int4* lab4 = (const int4*)label;
    int l[16];
#pragma unroll
    for (int r = 0; r < 4; r++) {
        int4 v = lab4[(4 * sy + r) * 128 + sx];
        l[4 * r + 0] = v.x; l[4 * r + 1] = v.y;
        l[4 * r + 2] = v.z; l[4 * r + 3] = v.w;
    }
#pragma unroll
    for (int c = 0; c < NCLS; c++) {
        int cc = 0;
#pragma unroll
        for (int j = 0; j < 16; j++) cc += (l[j] == c) ? 1 : 0;
        cnt[c * SRC + s] = (unsigned char)cc;
    }
}

// ---------------------------------------------------------------------------
// K2: moments. One 256-thread block (4 waves) per (c,d); 64 px/thread.
// unroll 4 (not 16!) keeps VGPRs <=64 so all 4864 waves are co-resident
// (launch_bounds(256,8) = 8 waves/EU cap). f32 thread partials -> f64
// shuffle reduce -> f64 LDS combine. No atomics.
// ---------------------------------------------------------------------------
__global__ __launch_bounds__(256, 8) void hl_moments_kernel(
    const float* __restrict__ feature, const unsigned char* __restrict__ cnt,
    double* __restrict__ S1, double* __restrict__ S2, int* __restrict__ ncls)
{
    int w = blockIdx.x;             // pair 0..1215
    int c = w >> 6, d = w & 63;
    int t = threadIdx.x;

    const float4*       fp4 = (const float4*)(feature + d * SRC);
    const unsigned int* cpu = (const unsigned int*)(cnt + c * SRC);

    float f1 = 0.f, f2 = 0.f;
    int   nc = 0;
#pragma unroll 4
    for (int i = 0; i < 16; i++) {
        int g = i * 256 + t;        // 4096 float4-groups (= 4096 uint groups)
        float4       x  = fp4[g];
        unsigned int cv = cpu[g];
        float xs[4] = {x.x, x.y, x.z, x.w};
        float cf[4] = {(float)(cv & 255u), (float)((cv >> 8) & 255u),
                       (float)((cv >> 16) & 255u), (float)(cv >> 24)};
#pragma unroll
        for (int e = 0; e < 4; e++) {
            float wx = cf[e] * xs[e];
            f1 += wx;
            f2 = fmaf(wx, xs[e], f2);
        }
        nc += (cv & 255u) + ((cv >> 8) & 255u) + ((cv >> 16) & 255u) + (cv >> 24);
    }
    double s1 = (double)f1, s2 = (double)f2;
#pragma unroll
    for (int o = 32; o > 0; o >>= 1) {
        s1 += __shfl_down(s1, o);
        s2 += __shfl_down(s2, o);
        nc += __shfl_down(nc, o);
    }
    __shared__ double ps1[4], ps2[4];
    __shared__ int    pn[4];
    int wid = t >> 6;
    if ((t & 63) == 0) { ps1[wid] = s1; ps2[wid] = s2; pn[wid] = nc; }
    __syncthreads();
    if (t == 0) {
        S1[w] = ps1[0] + ps1[1] + ps1[2] + ps1[3];
        S2[w] = ps2[0] + ps2[1] + ps2[2] + ps2[3];
        if (d == 0) ncls[c] = pn[0] + pn[1] + pn[2] + pn[3];
    }
}

// ---------------------------------------------------------------------------
// K3: KDE + per-pair loss. One 256-thread block per (c,d), 64 px/thread.
// unroll 2 keeps live set ~45 VGPRs; launch_bounds(256,8) caps at 64 so all
// blocks are resident (32 waves/CU) and the VALU stays fed. Bare v_exp_f32;
// C1*(u-k)^2 = q - 2k*p + C1*k^2 with p=C1*u, q=p*u (the 1/sqrt(2*pi*var_s)
// factor cancels in normalization). Block reduces its 7-bin histogram,
// computes its smooth-L1 partial, one f32 atomicAdd into out[0] (1216 adds,
// order noise ~1e-9 << 2.7e-7 budget). No fences.
// ---------------------------------------------------------------------------
__global__ __launch_bounds__(256, 8) void hl_kde_kernel(
    const float* __restrict__ feature, const unsigned char* __restrict__ cnt,
    const double* __restrict__ S1d, const double* __restrict__ S2d,
    const int* __restrict__ ncls, float* __restrict__ out)
{
    int w = blockIdx.x;             // pair 0..1215
    int c = w >> 6, d = w & 63;
    int t = threadIdx.x;
    int wid = t >> 6;

    __shared__ float sh_mu, sh_istd;
    __shared__ int   sh_act;
    if (t == 0) {
        int    n     = ncls[c];
        double nsafe = (n > 0) ? (double)n : 1.0;
        double s1 = S1d[w], s2 = S2d[w];
        double mu  = s1 / nsafe;
        double var = (s2 - 2.0 * mu * s1 + mu * mu * (double)n) / nsafe + 1e-10;
        sh_mu   = (float)mu;
        sh_istd = (float)(1.0 / sqrt(var));
        sh_act  = (n >= 1000);
    }
    __syncthreads();
    if (!sh_act) return;            // inactive class: contributes 0
    float istd = sh_istd;
    float nm   = -sh_mu * istd;     // u = fma(x, istd, nm)

    const float4*       fp4 = (const float4*)(feature + d * SRC);
    const unsigned int* cpu = (const unsigned int*)(cnt + c * SRC);

    const float C1 = -18.033688011112042f;   // -12.5 * log2(e)
    float acc[7] = {0.f, 0.f, 0.f, 0.f, 0.f, 0.f, 0.f};

#pragma unroll 2
    for (int i = 0; i < 16; i++) {
        int g = i * 256 + t;
        float4       x  = fp4[g];
        unsigned int cv = cpu[g];
        float xs[4] = {x.x, x.y, x.z, x.w};
        float cf[4] = {(float)(cv & 255u), (float)((cv >> 8) & 255u),
                       (float)((cv >> 16) & 255u), (float)(cv >> 24)};
#pragma unroll
        for (int e = 0; e < 4; e++) {
            float u = fmaf(xs[e], istd, nm);
            float p = C1 * u;
            float q = p * u;                 // C1*u^2
#pragma unroll
            for (int k = 0; k < 7; k++) {
                float km  = (float)(k - 3);
                float arg = fmaf(p, -2.f * km, q + C1 * km * km);
                acc[k] = fmaf(cf[e], EXP2F(arg), acc[k]);
            }
        }
    }

    __shared__ float part[4][7];
#pragma unroll
    for (int j = 0; j < 7; j++) {
        float v = acc[j];
#pragma unroll
        for (int o = 32; o > 0; o >>= 1) v += __shfl_down(v, o);
        if ((t & 63) == 0) part[wid][j] = v;
    }
    __syncthreads();

    if (t == 0) {
        // target: exp(-0.5 k^2)/Z (1/sqrt(2 pi var) cancels in normalization)
        double e[7], z = 0.0;
#pragma unroll
        for (int k = -3; k <= 3; k++) { e[k + 3] = exp(-0.5 * (double)(k * k)); z += e[k + 3]; }

        float hist[7], S = 0.f;
#pragma unroll
        for (int j = 0; j < 7; j++) {
            hist[j] = part[0][j] + part[1][j] + part[2][j] + part[3][j];
            S += hist[j];
        }
        float Ss = fmaxf(S, 1e-30f);
        float ps = 0.f;
#pragma unroll
        for (int j = 0; j < 7; j++) {
            float dd = fabsf(hist[j] / Ss - (float)(e[j] / z));
            ps += (dd < 1.f) ? 0.5f * dd * dd : (dd - 0.5f);
        }
        int A = 0;
#pragma unroll
        for (int i = 0; i < NCLS; i++) A += (ncls[i] >= 1000) ? 1 : 0;
        atomicAdd(out, ps / (448.0f * (float)A));
    }
}

// ---------------------------------------------------------------------------
extern "C" void kernel_launch(void* const* d_in, const int* in_sizes, int n_in,
                              void* d_out, int out_size, void* d_ws, size_t ws_size,
                              hipStream_t stream)
{
    const float* feature = (const float*)d_in[0];   // [1,64,128,128] fp32
    const int*   label   = (const int*)d_in[1];     // [1,1,512,512]  int32
    float*       out     = (float*)d_out;           // scalar fp32

    char* ws = (char*)d_ws;
    unsigned char* cnt  = (unsigned char*)(ws);      // 311296 B
    double*        S1   = (double*)(ws + 311296);    // 9728 B
    double*        S2   = (double*)(ws + 321024);    // 9728 B
    int*           ncls = (int*)(ws + 330752);       // 76 B

    hl_count_kernel  <<<SRC / 256, 256, 0, stream>>>(label, cnt, out);
    hl_moments_kernel<<<NPAIR, 256, 0, stream>>>(feature, cnt, S1, S2, ncls);
    hl_kde_kernel    <<<NPAIR, 256, 0, stream>>>(feature, cnt, S1, S2, ncls, out);
}